// Round 16
// baseline (334.061 us; speedup 1.0000x reference)
//
#include <hip/hip_runtime.h>

constexpr int kN = 100000;
constexpr int kNpad = 100096;      // 391 tiles of 256
constexpr int kE = 800000;
constexpr int kB = 128;
constexpr int kBinsPerDir = 391;   // ceil(100000/256)
constexpr int kNB = 782;           // 2 * 391
constexpr int kRep = 64;
constexpr int kCtrs = kNB * kRep;  // 50048
constexpr int kTiles = kNpad / 256; // 391 tiles per direction
constexpr float kInvBN = 0.99999500003749968f; // 1/sqrt(1+1e-5)

// prep phases: grid-stride, high per-thread intensity
constexpr int kXconvBlocks = 1024;
constexpr int kWprepBlocks = 192;
constexpr int kBincountBlocks = 782;
constexpr int kGstartBlocks = 391;
constexpr int kPrepBlocks = kXconvBlocks + kWprepBlocks + kBincountBlocks + kGstartBlocks;

typedef short s16x8 __attribute__((ext_vector_type(8)));
typedef float f32x4 __attribute__((ext_vector_type(4)));

__device__ inline ushort bf16rne(float f) {
  uint u = __builtin_bit_cast(uint, f);
  u += 0x7fffu + ((u >> 16) & 1u);
  return (ushort)(u >> 16);
}
__device__ inline float bflo(uint v) { return __builtin_bit_cast(float, v << 16); }
__device__ inline float bfhi(uint v) { return __builtin_bit_cast(float, v & 0xffff0000u); }
__device__ inline uint pack2(float a, float b) {
  return (uint)bf16rne(a) | ((uint)bf16rne(b) << 16);
}

struct WPtrs { const float* Wl[6]; const float* Wr[6]; };

// ---------------- fused prep: xconv | wprep | bincount | gstart ----------------

__global__ __launch_bounds__(256) void prep_kernel(
    const float* __restrict__ x, ushort* __restrict__ xb,
    WPtrs p, ushort* __restrict__ Wb,
    const int* __restrict__ ei, const int* __restrict__ ed,
    int* __restrict__ bincnt,
    const int* __restrict__ batch, int* __restrict__ gstart) {
  int bi = blockIdx.x;
  int t = threadIdx.x;
  if (bi < kXconvBlocks) {
    constexpr int total = kNpad * 128 / 8;
    constexpr int stride = kXconvBlocks * 256;
    for (int i = bi * 256 + t; i < total; i += stride) {
      int i8 = i * 8;
      ushort4 r0, r1;
      if (i8 < kN * 128) {
        float4 v0 = *(const float4*)&x[i8];
        float4 v1 = *(const float4*)&x[i8 + 4];
        r0.x = bf16rne(v0.x); r0.y = bf16rne(v0.y); r0.z = bf16rne(v0.z); r0.w = bf16rne(v0.w);
        r1.x = bf16rne(v1.x); r1.y = bf16rne(v1.y); r1.z = bf16rne(v1.z); r1.w = bf16rne(v1.w);
      } else {
        r0.x = r0.y = r0.z = r0.w = 0;
        r1 = r0;
      }
      *(ushort4*)&xb[i8] = r0;
      *(ushort4*)&xb[i8 + 4] = r1;
    }
  } else if (bi < kXconvBlocks + kWprepBlocks) {
    int id4 = ((bi - kXconvBlocks) * 256 + t) * 4;
    int L = id4 >> 15;
    int o = (id4 >> 8) & 127, k = id4 & 255;
    const float* src = (k < 128) ? p.Wl[L] : p.Wr[L];
    float4 v = *(const float4*)&src[o * 128 + (k & 127)];
    ushort4 r;
    r.x = bf16rne(v.x); r.y = bf16rne(v.y); r.z = bf16rne(v.z); r.w = bf16rne(v.w);
    *(ushort4*)&Wb[id4] = r;
  } else if (bi < kXconvBlocks + kWprepBlocks + kBincountBlocks) {
    int e4 = ((bi - kXconvBlocks - kWprepBlocks) * 256 + t) * 4;
    if (e4 < kE) {
      int4 dv = *(const int4*)&ed[e4];
      int4 sv = *(const int4*)&ei[kE + e4];
      int dsts[4] = {sv.x, sv.y, sv.z, sv.w};
      int dirs[4] = {dv.x, dv.y, dv.z, dv.w};
#pragma unroll
      for (int k = 0; k < 4; ++k) {
        int e = e4 + k;
        if (e < kE) {
          int ctr = ((dirs[k] * kBinsPerDir + (dsts[k] >> 8)) << 6) | ((e >> 8) & 63);
          atomicAdd(&bincnt[ctr], 1);
        }
      }
    }
  } else {
    int n = (bi - kXconvBlocks - kWprepBlocks - kBincountBlocks) * 256 + t;
    if (n < kN) {
      int b = batch[n];
      int bprev = (n == 0) ? -1 : batch[n - 1];
      for (int g = bprev + 1; g <= b; ++g) gstart[g] = n;
      if (n == kN - 1)
        for (int g = b + 1; g <= kB; ++g) gstart[g] = kN;
    }
  }
}

// ---------------- scans ----------------

__global__ __launch_bounds__(256) void scan1_kernel(const int* __restrict__ in,
                                                    int* __restrict__ out,
                                                    int* __restrict__ bsum, int M) {
  __shared__ int s[256];
  int t = threadIdx.x;
  int idx = blockIdx.x * 1024 + t * 4;
  int4 v = {0, 0, 0, 0};
  if (idx < M) v = *(const int4*)&in[idx];
  int tsum = v.x + v.y + v.z + v.w;
  s[t] = tsum;
  __syncthreads();
  for (int d = 1; d < 256; d <<= 1) {
    int tmp = (t >= d) ? s[t - d] : 0;
    __syncthreads();
    s[t] += tmp;
    __syncthreads();
  }
  int excl = s[t] - tsum;
  if (idx < M) {
    int4 o;
    o.x = excl; o.y = excl + v.x; o.z = o.y + v.y; o.w = o.z + v.z;
    *(int4*)&out[idx] = o;
  }
  if (t == 255) bsum[blockIdx.x] = s[255];
}

__global__ __launch_bounds__(256) void scan2_kernel(int* __restrict__ bsum, int nb,
                                                    int* __restrict__ ghist) {
  __shared__ int s[256];
  int t = threadIdx.x;
  if (t < 128) ghist[t] = 0;
  int v = (t < nb) ? bsum[t] : 0;
  s[t] = v;
  __syncthreads();
  for (int d = 1; d < 256; d <<= 1) {
    int tmp = (t >= d) ? s[t - d] : 0;
    __syncthreads();
    s[t] += tmp;
    __syncthreads();
  }
  if (t < nb) bsum[t] = s[t] - v;
}

__global__ __launch_bounds__(256) void scan3_kernel(int* __restrict__ out,
                                                    const int* __restrict__ bsum, int M,
                                                    int* __restrict__ bincur) {
  int idx = blockIdx.x * 1024 + threadIdx.x * 4;
  int add = bsum[blockIdx.x];
  if (idx < M) {
    int4 o = *(int4*)&out[idx];
    o.x += add; o.y += add; o.z += add; o.w += add;
    *(int4*)&out[idx] = o;
    int4 z = {0, 0, 0, 0};
    *(int4*)&bincur[idx] = z;
  }
}

// ---------------- two-level sort: scatter + dense fill ----------------

__global__ __launch_bounds__(256) void binscatter_kernel(const int* __restrict__ ei,
                                                         const int* __restrict__ ed,
                                                         const int* __restrict__ binoff,
                                                         int* __restrict__ bincur,
                                                         uint* __restrict__ binbuf,
                                                         float* __restrict__ comb_raw) {
  int gid = blockIdx.x * 256 + threadIdx.x;
  if (gid < kB * 256 / 4) {
    float4 z = {0.f, 0.f, 0.f, 0.f};
    *(float4*)&comb_raw[gid * 4] = z;
  }
  if (gid >= kE) return;
  int dst = ei[kE + gid];
  int ctr = ((ed[gid] * kBinsPerDir + (dst >> 8)) << 6) | ((gid >> 8) & 63);
  int pos = atomicAdd(&bincur[ctr], 1);
  binbuf[binoff[ctr] + pos] = (uint)ei[gid] | ((uint)(dst & 255) << 17);
}

__global__ __launch_bounds__(256) void binfill_kernel(const uint* __restrict__ binbuf,
                                                      const int* __restrict__ binoff,
                                                      int* __restrict__ csr,
                                                      int* __restrict__ cnt,
                                                      int* __restrict__ off,
                                                      int* __restrict__ ghist,
                                                      int* __restrict__ blockbase,
                                                      uint* __restrict__ perm) {
  __shared__ int lcnt[256];
  __shared__ int ls[256];
  __shared__ int lpos[256];
  int b = blockIdx.x;
  int t = threadIdx.x;
  perm[b * 256 + t] = (uint)kN;   // sentinel prefill (782*256 == 2*kNpad)
  int dir = (b >= kBinsPerDir) ? 1 : 0;
  int nodeBase = (b - dir * kBinsPerDir) << 8;
  int e0 = binoff[b * kRep];
  int e1 = (b == kNB - 1) ? kE : binoff[(b + 1) * kRep];
  lcnt[t] = 0;
  __syncthreads();
  for (int e = e0 + t; e < e1; e += 256) atomicAdd(&lcnt[binbuf[e] >> 17], 1);
  __syncthreads();
  int my = lcnt[t];
  ls[t] = my;
  __syncthreads();
  for (int d = 1; d < 256; d <<= 1) {
    int tmp = (t >= d) ? ls[t - d] : 0;
    __syncthreads();
    ls[t] += tmp;
    __syncthreads();
  }
  int excl = ls[t] - my;
  lpos[t] = e0 + excl;
  int node = nodeBase + t;
  if (node < kN) {
    int g = dir * kN + node;
    cnt[g] = my;
    off[g] = e0 + excl;
  }
  if (t < 64) lcnt[t] = 0;
  __syncthreads();
  if (node < kN) atomicAdd(&lcnt[min(my, 63)], 1);
  __syncthreads();
  if (t < 64) blockbase[b * 64 + t] = atomicAdd(&ghist[dir * 64 + t], lcnt[t]);
  __syncthreads();
  for (int e = e0 + t; e < e1; e += 256) {
    uint v = binbuf[e];
    int pos = atomicAdd(&lpos[v >> 17], 1);
    csr[pos] = (int)(v & 0x1FFFFu);
  }
}

// ---------------- degree-sort finish: scan + DESCENDING (LPT) scatter ----------------

__global__ __launch_bounds__(64) void dscan_kernel(int* __restrict__ ghist) {
  __shared__ int s[64];
  int t = threadIdx.x;
  for (int dir = 0; dir < 2; ++dir) {
    int v = ghist[dir * 64 + t];
    s[t] = v;
    __syncthreads();
    for (int d = 1; d < 64; d <<= 1) {
      int tmp = (t >= d) ? s[t - d] : 0;
      __syncthreads();
      s[t] += tmp;
      __syncthreads();
    }
    ghist[dir * 64 + t] = s[t] - v;
    __syncthreads();
  }
}

// descending-degree order: uniform-degree blocks, longest first (LPT).
__global__ __launch_bounds__(256) void dscatter_kernel(const int* __restrict__ cnt,
                                                       const int* __restrict__ ghist,
                                                       const int* __restrict__ blockbase,
                                                       uint* __restrict__ perm) {
  __shared__ int h[64];
  int b = blockIdx.x;
  int t = threadIdx.x;
  int dir = (b >= kBinsPerDir) ? 1 : 0;
  int node = (b - dir * kBinsPerDir) * 256 + t;
  if (t < 64) h[t] = 0;
  __syncthreads();
  if (node < kN) {
    int bucket = min(cnt[dir * kN + node], 63);
    int r = atomicAdd(&h[bucket], 1);
    int pos = ghist[dir * 64 + bucket] + blockbase[b * 64 + bucket] + r;
    perm[dir * kNpad + (kN - 1 - pos)] = (uint)node;
  }
}

// ---------------- Fused SAGE layer: persistent blocks, W staged ONCE ----------------
// Grid = 512 (2/CU). Block b: dir = b>>8, tiles {bb, 390-bb} (LPT pairing).

__global__ __launch_bounds__(1024) void fused_layer_kernel(
    const ushort* __restrict__ hin0, const ushort* __restrict__ hin1,
    ushort* __restrict__ hout0, ushort* __restrict__ hout1,
    const ushort* __restrict__ Wb0, const ushort* __restrict__ Wb1,
    const float* __restrict__ bl0, const float* __restrict__ bl1,
    const int* __restrict__ off, const int* __restrict__ cnt,
    const int* __restrict__ csr, const uint* __restrict__ perm) {
  __shared__ ushort Wlds[128 * 256];   // 64 KB, 16B-block XOR swizzled

  const int bb = blockIdx.x & 255;
  const int dir = blockIdx.x >> 8;
  const ushort* __restrict__ h = dir ? hin1 : hin0;
  ushort* __restrict__ outp = dir ? hout1 : hout0;
  const ushort* __restrict__ Wb = dir ? Wb1 : Wb0;
  const float* __restrict__ bl = dir ? bl1 : bl0;
  const uint* __restrict__ pp = perm + (size_t)dir * kNpad;
  const int dirbase = dir * kN;

  const int t = threadIdx.x;
  const int w = t >> 6;         // 0..15
  const int l = t & 63;
  const int lr = l & 15;
  const int lq = l >> 4;
  const int swz = lr & 7;

  // stage W once per block, barrier right after
#pragma unroll
  for (int it = 0; it < 4; ++it) {
    int u = t + 1024 * it;  // u < 4096 16B-chunks
    int o = u >> 5, b = u & 31;
    uint4 v = *(const uint4*)(Wb + (size_t)u * 8);
    *(uint4*)((char*)Wlds + o * 512 + ((b ^ (o & 7)) << 4)) = v;
  }
  __syncthreads();

  for (int pass = 0; pass < 2; ++pass) {
    if (pass == 1 && bb >= kTiles - 256) break;   // 391-256=135 blocks get 2 tiles
    const int tile = (pass == 0) ? bb : (kTiles - 1 - bb);

    const int node = (int)pp[tile * 256 + w * 16 + lr];  // pad -> kN
    int s = 0, c = 0;
    if (node < kN) {
      int bkt = dirbase + node;
      s = off[bkt];
      c = cnt[bkt];
    }
    s16x8 self[4];
#pragma unroll
    for (int q = 0; q < 4; ++q)
      self[q] = *(const s16x8*)(h + (size_t)node * 128 + q * 32 + lq * 8);

    // ---- gather + mean (registers only; no barriers) ----
    float ga[32];
#pragma unroll
    for (int i = 0; i < 32; ++i) ga[i] = 0.f;
    {
      const ushort* hp = h + lq * 8;
      int e = 0;
      for (; e + 2 <= c; e += 2) {
        int s0 = csr[s + e];
        int s1 = csr[s + e + 1];
        const ushort* p0 = hp + (size_t)s0 * 128;
        const ushort* p1 = hp + (size_t)s1 * 128;
        uint4 va[4], vb[4];
#pragma unroll
        for (int q = 0; q < 4; ++q) va[q] = *(const uint4*)(p0 + q * 32);
#pragma unroll
        for (int q = 0; q < 4; ++q) vb[q] = *(const uint4*)(p1 + q * 32);
#pragma unroll
        for (int q = 0; q < 4; ++q) {
          ga[q * 8 + 0] += bflo(va[q].x) + bflo(vb[q].x);
          ga[q * 8 + 1] += bfhi(va[q].x) + bfhi(vb[q].x);
          ga[q * 8 + 2] += bflo(va[q].y) + bflo(vb[q].y);
          ga[q * 8 + 3] += bfhi(va[q].y) + bfhi(vb[q].y);
          ga[q * 8 + 4] += bflo(va[q].z) + bflo(vb[q].z);
          ga[q * 8 + 5] += bfhi(va[q].z) + bfhi(vb[q].z);
          ga[q * 8 + 6] += bflo(va[q].w) + bflo(vb[q].w);
          ga[q * 8 + 7] += bfhi(va[q].w) + bfhi(vb[q].w);
        }
      }
      if (e < c) {
        int s0 = csr[s + e];
        const ushort* p0 = hp + (size_t)s0 * 128;
        uint4 va[4];
#pragma unroll
        for (int q = 0; q < 4; ++q) va[q] = *(const uint4*)(p0 + q * 32);
#pragma unroll
        for (int q = 0; q < 4; ++q) {
          ga[q * 8 + 0] += bflo(va[q].x);
          ga[q * 8 + 1] += bfhi(va[q].x);
          ga[q * 8 + 2] += bflo(va[q].y);
          ga[q * 8 + 3] += bfhi(va[q].y);
          ga[q * 8 + 4] += bflo(va[q].z);
          ga[q * 8 + 5] += bfhi(va[q].z);
          ga[q * 8 + 6] += bflo(va[q].w);
          ga[q * 8 + 7] += bfhi(va[q].w);
        }
      }
    }
    float iv = 1.0f / fmaxf((float)c, 1.0f);
    s16x8 am[4];
#pragma unroll
    for (int q = 0; q < 4; ++q) {
      uint4 r;
      r.x = pack2(ga[q * 8 + 0] * iv, ga[q * 8 + 1] * iv);
      r.y = pack2(ga[q * 8 + 2] * iv, ga[q * 8 + 3] * iv);
      r.z = pack2(ga[q * 8 + 4] * iv, ga[q * 8 + 5] * iv);
      r.w = pack2(ga[q * 8 + 6] * iv, ga[q * 8 + 7] * iv);
      am[q] = __builtin_bit_cast(s16x8, r);
    }

    // ---- MFMA: 16 nodes x 128 outs, K=256 (mean regs | self regs) ----
    f32x4 acc[8];
#pragma unroll
    for (int j = 0; j < 8; ++j) acc[j] = {0.f, 0.f, 0.f, 0.f};

#pragma unroll
    for (int kk = 0; kk < 8; ++kk) {
      s16x8 a = (kk < 4) ? am[kk] : self[kk - 4];
      const int ks = (kk * 4 + lq) ^ swz;
#pragma unroll
      for (int j = 0; j < 8; ++j) {
        int o = j * 16 + lr;
        s16x8 wf = *(const s16x8*)((const char*)Wlds + o * 512 + (ks << 4));
        acc[j] = __builtin_amdgcn_mfma_f32_16x16x32_bf16(wf, a, acc[j], 0, 0, 0);
      }
    }

    if (node < kN) {
#pragma unroll
      for (int j = 0; j < 8; ++j) {
        int o = j * 16 + lq * 4;
        float4 bv = *(const float4*)(bl + o);
        ushort4 r;
        r.x = bf16rne(fmaxf(acc[j][0] + bv.x, 0.f));
        r.y = bf16rne(fmaxf(acc[j][1] + bv.y, 0.f));
        r.z = bf16rne(fmaxf(acc[j][2] + bv.z, 0.f));
        r.w = bf16rne(fmaxf(acc[j][3] + bv.w, 0.f));
        *(ushort4*)(outp + (size_t)node * 128 + o) = r;
      }
    }
  }
}

// ---------------- Pooling: both directions, 16 chunks per graph ----------------

__global__ __launch_bounds__(256) void pool_kernel(const ushort* __restrict__ hp0,
                                                   const ushort* __restrict__ hp1,
                                                   const int* __restrict__ gstart,
                                                   float* __restrict__ comb_raw) {
  __shared__ float part[4 * 128];
  int gb = blockIdx.x;
  int dir = gb >> 11;            // kB*16 = 2048 blocks per dir
  int rem = gb & 2047;
  int graph = rem >> 4;
  int chunk = rem & 15;
  const ushort* __restrict__ h = dir ? hp1 : hp0;
  int base = dir << 7;
  int t = threadIdx.x;
  int slice = t >> 6;
  int col = t & 63;
  int s = gstart[graph];
  int e = gstart[graph + 1];
  int len = e - s;
  int c0 = s + (int)((long long)len * chunk / 16);
  int c1 = s + (int)((long long)len * (chunk + 1) / 16);
  float ax = 0.f, ay = 0.f;
  for (int n = c0 + slice; n < c1; n += 4) {
    uint v = *(const uint*)(h + (size_t)n * 128 + col * 2);
    ax += bflo(v);
    ay += bfhi(v);
  }
  part[slice * 128 + col * 2] = ax;
  part[slice * 128 + col * 2 + 1] = ay;
  __syncthreads();
  if (t < 128) {
    float v = part[t] + part[128 + t] + part[256 + t] + part[384 + t];
    atomicAdd(&comb_raw[graph * 256 + base + t], v);
  }
}

// ---------------- Heads ----------------

__global__ __launch_bounds__(256) void head_kernel(
    const float* __restrict__ comb_raw, const int* __restrict__ gstart,
    const float* __restrict__ gf,
    const float* __restrict__ neg, const float* __restrict__ neb,
    const float* __restrict__ fc1W, const float* __restrict__ fc1b,
    const float* __restrict__ bn1g, const float* __restrict__ bn1b,
    const float* __restrict__ fc2W, const float* __restrict__ fc2b,
    const float* __restrict__ fc3aW, const float* __restrict__ fc3ab,
    const float* __restrict__ fc3bW, const float* __restrict__ fc3bb,
    const float* __restrict__ ncg, const float* __restrict__ ncb,
    float* __restrict__ out) {
  __shared__ float wlds[6979];
  __shared__ float comb[256];
  __shared__ float x3[261];
  __shared__ float r2s[2];

  const int b = blockIdx.x;
  const int t = threadIdx.x;

  for (int i = t; i < 4112; i += 256) wlds[i] = fc1W[i];
  for (int i = t; i < 518; i += 256) wlds[4112 + i] = fc2W[i];
  for (int i = t; i < 1044; i += 256) wlds[4630 + i] = fc3aW[i];
  for (int i = t; i < 1305; i += 256) wlds[5674 + i] = fc3bW[i];

  float cntf = fmaxf((float)(gstart[b + 1] - gstart[b]), 1.0f);
  if (t < 256) comb[t] = neg[t] * ((comb_raw[b * 256 + t] / cntf) * kInvBN) + neb[t];
  __syncthreads();

  float g1 = gf[b * 5 + 1], g2 = gf[b * 5 + 2], g3 = gf[b * 5 + 3], g4 = gf[b * 5 + 4];
  const int g = t >> 3, l8 = t & 7;

  {
    float p = 0.f;
    if (g < 16) {
      const float* w = &wlds[g * 257];
      for (int j = l8; j < 256; j += 8) p += comb[j] * w[j];
    } else if (g < 18) {
      const float* w = &wlds[4112 + (g - 16) * 259];
      for (int j = l8; j < 256; j += 8) p += comb[j] * w[j];
    }
    p += __shfl_xor(p, 1);
    p += __shfl_xor(p, 2);
    p += __shfl_xor(p, 4);
    if (l8 == 0) {
      if (g < 16) {
        float z = fmaxf(p + wlds[g * 257 + 256] * g4 + fc1b[g], 0.f);
        out[b * 16 + g] = bn1g[g] * (z * kInvBN) + bn1b[g];
      } else if (g < 18) {
        int o = g - 16;
        const float* w = &wlds[4112 + o * 259];
        float z = fmaxf(p + w[256] * g2 + w[257] * g3 + w[258] * g4 + fc2b[o], 0.f);
        out[2048 + b * 2 + o] = z;
        r2s[o] = z;
      }
    }
  }
  for (int j = t; j < 261; j += 256) {
    float v;
    if (j < 256) v = comb[j];
    else if (j == 256) v = g2;
    else if (j == 257) v = g1;
    else if (j == 258) v = g2;
    else if (j == 259) v = g3;
    else v = g4;
    x3[j] = ncg[j] * (v * kInvBN) + ncb[j];
  }
  __syncthreads();
  int pred = (r2s[1] > r2s[0]) ? 1 : 0;

  {
    float p = 0.f;
    if (g < 4) {
      const float* w = &wlds[4630 + g * 261];
      for (int j = l8; j < 261; j += 8) p += x3[j] * w[j];
    } else if (g < 9) {
      const float* w = &wlds[5674 + (g - 4) * 261];
      for (int j = l8; j < 261; j += 8) p += x3[j] * w[j];
    }
    p += __shfl_xor(p, 1);
    p += __shfl_xor(p, 2);
    p += __shfl_xor(p, 4);
    if (l8 == 0) {
      if (g < 4) {
        float v = p + fc3ab[g];
        out[2304 + b * 9 + g] = (pred == 0) ? v : 0.f;
      } else if (g < 9) {
        int o = g - 4;
        float v = p + fc3bb[o];
        out[2304 + b * 9 + 4 + o] = (pred == 1) ? v : 0.f;
      }
    }
  }
}

// ---------------- Launch ----------------

extern "C" void kernel_launch(void* const* d_in, const int* in_sizes, int n_in,
                              void* d_out, int out_size, void* d_ws, size_t ws_size,
                              hipStream_t stream) {
  (void)in_sizes; (void)n_in; (void)out_size; (void)ws_size;
  const float* x   = (const float*)d_in[0];
  const int* ei    = (const int*)d_in[1];
  const int* ed    = (const int*)d_in[2];
  const int* batch = (const int*)d_in[3];
  const float* gf  = (const float*)d_in[4];

  char* ws = (char*)d_ws;
  auto carve = [&](size_t bytes) -> void* {
    void* p = ws;
    ws += (bytes + 255) & ~(size_t)255;
    return p;
  };
  int* cnt        = (int*)carve(2 * kN * sizeof(int));
  int* off        = (int*)carve(2 * kN * sizeof(int));
  int* bincnt     = (int*)carve(kCtrs * sizeof(int));
  int* bincur     = (int*)carve((kCtrs + 4) * sizeof(int));
  int* binoff     = (int*)carve((kCtrs + 4) * sizeof(int));
  int* bsum       = (int*)carve(1024);
  int* gstart     = (int*)carve((kB + 1) * sizeof(int));
  int* ghist      = (int*)carve(128 * sizeof(int));
  int* blockbase  = (int*)carve(kNB * 64 * sizeof(int));
  uint* perm      = (uint*)carve(2 * kNpad * sizeof(uint));
  int* csr        = (int*)carve(kE * sizeof(int));
  uint* binbuf    = (uint*)carve(kE * sizeof(uint));
  float* comb_raw = (float*)carve(kB * 256 * sizeof(float));
  ushort* xb      = (ushort*)carve((size_t)kNpad * 128 * 2);  // also reused as s1
  ushort* p0      = (ushort*)carve((size_t)kNpad * 128 * 2);
  ushort* p1      = (ushort*)carve((size_t)kNpad * 128 * 2);
  ushort* s0      = (ushort*)carve((size_t)kNpad * 128 * 2);
  ushort* Wb      = (ushort*)carve(6 * 128 * 256 * 2);

  hipMemsetAsync(bincnt, 0, kCtrs * sizeof(int), stream);

  WPtrs wp;
  for (int L = 0; L < 6; ++L) {
    wp.Wl[L] = (const float*)d_in[6 + 3 * L];
    wp.Wr[L] = (const float*)d_in[6 + 3 * L + 2];
  }

  prep_kernel<<<kPrepBlocks, 256, 0, stream>>>(x, xb, wp, Wb, ei, ed, bincnt, batch, gstart);

  constexpr int NBScan = (kCtrs + 1023) / 1024;  // 49
  scan1_kernel<<<NBScan, 256, 0, stream>>>(bincnt, binoff, bsum, kCtrs);
  scan2_kernel<<<1, 256, 0, stream>>>(bsum, NBScan, ghist);
  scan3_kernel<<<NBScan, 256, 0, stream>>>(binoff, bsum, kCtrs, bincur);
  binscatter_kernel<<<(kE + 255) / 256, 256, 0, stream>>>(ei, ed, binoff, bincur, binbuf, comb_raw);
  binfill_kernel<<<kNB, 256, 0, stream>>>(binbuf, binoff, csr, cnt, off, ghist, blockbase, perm);
  dscan_kernel<<<1, 64, 0, stream>>>(ghist);
  dscatter_kernel<<<kNB, 256, 0, stream>>>(cnt, ghist, blockbase, perm);

  auto W = [&](int L) { return Wb + (size_t)L * 32768; };
  auto B = [&](int L) { return (const float*)d_in[6 + 3 * L + 1]; };

  // L0: pre xb->p0, suc xb->s0
  fused_layer_kernel<<<512, 1024, 0, stream>>>(
      xb, xb, p0, s0, W(0), W(3), B(0), B(3), off, cnt, csr, perm);
  // L1: pre p0->p1, suc s0->xb (xb reused as s1)
  fused_layer_kernel<<<512, 1024, 0, stream>>>(
      p0, s0, p1, xb, W(1), W(4), B(1), B(4), off, cnt, csr, perm);
  // L2: pre p1->p0, suc xb->s0
  fused_layer_kernel<<<512, 1024, 0, stream>>>(
      p1, xb, p0, s0, W(2), W(5), B(2), B(5), off, cnt, csr, perm);

  pool_kernel<<<2 * kB * 16, 256, 0, stream>>>(p0, s0, gstart, comb_raw);

  head_kernel<<<kB, 256, 0, stream>>>(
      comb_raw, gstart, gf,
      (const float*)d_in[24], (const float*)d_in[25],
      (const float*)d_in[26], (const float*)d_in[27],
      (const float*)d_in[28], (const float*)d_in[29],
      (const float*)d_in[30], (const float*)d_in[31],
      (const float*)d_in[32], (const float*)d_in[33],
      (const float*)d_in[34], (const float*)d_in[35],
      (const float*)d_in[36], (const float*)d_in[37],
      (float*)d_out);
}

// Round 17
// 324.660 us; speedup vs baseline: 1.0290x; 1.0290x over previous
//
#include <hip/hip_runtime.h>

constexpr int kN = 100000;
constexpr int kNpad = 100096;      // 391 tiles of 256
constexpr int kE = 800000;
constexpr int kB = 128;
constexpr int kBinsPerDir = 391;   // ceil(100000/256)
constexpr int kNB = 782;           // 2 * 391
constexpr int kRep = 64;
constexpr int kCtrs = kNB * kRep;  // 50048
constexpr int kTiles = kNpad / 256; // 391 tiles per direction
constexpr float kInvBN = 0.99999500003749968f; // 1/sqrt(1+1e-5)

// prep phases: grid-stride, high per-thread intensity
constexpr int kXconvBlocks = 1024;
constexpr int kWprepBlocks = 192;
constexpr int kBincountBlocks = 782;
constexpr int kGstartBlocks = 391;
constexpr int kPrepBlocks = kXconvBlocks + kWprepBlocks + kBincountBlocks + kGstartBlocks;

typedef short s16x8 __attribute__((ext_vector_type(8)));
typedef float f32x4 __attribute__((ext_vector_type(4)));

__device__ inline ushort bf16rne(float f) {
  uint u = __builtin_bit_cast(uint, f);
  u += 0x7fffu + ((u >> 16) & 1u);
  return (ushort)(u >> 16);
}
__device__ inline float bflo(uint v) { return __builtin_bit_cast(float, v << 16); }
__device__ inline float bfhi(uint v) { return __builtin_bit_cast(float, v & 0xffff0000u); }
__device__ inline uint pack2(float a, float b) {
  return (uint)bf16rne(a) | ((uint)bf16rne(b) << 16);
}

struct WPtrs { const float* Wl[6]; const float* Wr[6]; };

// ---------------- fused prep: xconv | wprep | bincount | gstart ----------------

__global__ __launch_bounds__(256) void prep_kernel(
    const float* __restrict__ x, ushort* __restrict__ xb,
    WPtrs p, ushort* __restrict__ Wb,
    const int* __restrict__ ei, const int* __restrict__ ed,
    int* __restrict__ bincnt,
    const int* __restrict__ batch, int* __restrict__ gstart) {
  int bi = blockIdx.x;
  int t = threadIdx.x;
  if (bi < kXconvBlocks) {
    constexpr int total = kNpad * 128 / 8;
    constexpr int stride = kXconvBlocks * 256;
    for (int i = bi * 256 + t; i < total; i += stride) {
      int i8 = i * 8;
      ushort4 r0, r1;
      if (i8 < kN * 128) {
        float4 v0 = *(const float4*)&x[i8];
        float4 v1 = *(const float4*)&x[i8 + 4];
        r0.x = bf16rne(v0.x); r0.y = bf16rne(v0.y); r0.z = bf16rne(v0.z); r0.w = bf16rne(v0.w);
        r1.x = bf16rne(v1.x); r1.y = bf16rne(v1.y); r1.z = bf16rne(v1.z); r1.w = bf16rne(v1.w);
      } else {
        r0.x = r0.y = r0.z = r0.w = 0;
        r1 = r0;
      }
      *(ushort4*)&xb[i8] = r0;
      *(ushort4*)&xb[i8 + 4] = r1;
    }
  } else if (bi < kXconvBlocks + kWprepBlocks) {
    int id4 = ((bi - kXconvBlocks) * 256 + t) * 4;
    int L = id4 >> 15;
    int o = (id4 >> 8) & 127, k = id4 & 255;
    const float* src = (k < 128) ? p.Wl[L] : p.Wr[L];
    float4 v = *(const float4*)&src[o * 128 + (k & 127)];
    ushort4 r;
    r.x = bf16rne(v.x); r.y = bf16rne(v.y); r.z = bf16rne(v.z); r.w = bf16rne(v.w);
    *(ushort4*)&Wb[id4] = r;
  } else if (bi < kXconvBlocks + kWprepBlocks + kBincountBlocks) {
    int e4 = ((bi - kXconvBlocks - kWprepBlocks) * 256 + t) * 4;
    if (e4 < kE) {
      int4 dv = *(const int4*)&ed[e4];
      int4 sv = *(const int4*)&ei[kE + e4];
      int dsts[4] = {sv.x, sv.y, sv.z, sv.w};
      int dirs[4] = {dv.x, dv.y, dv.z, dv.w};
#pragma unroll
      for (int k = 0; k < 4; ++k) {
        int e = e4 + k;
        if (e < kE) {
          int ctr = ((dirs[k] * kBinsPerDir + (dsts[k] >> 8)) << 6) | ((e >> 8) & 63);
          atomicAdd(&bincnt[ctr], 1);
        }
      }
    }
  } else {
    int n = (bi - kXconvBlocks - kWprepBlocks - kBincountBlocks) * 256 + t;
    if (n < kN) {
      int b = batch[n];
      int bprev = (n == 0) ? -1 : batch[n - 1];
      for (int g = bprev + 1; g <= b; ++g) gstart[g] = n;
      if (n == kN - 1)
        for (int g = b + 1; g <= kB; ++g) gstart[g] = kN;
    }
  }
}

// ---------------- scans ----------------

__global__ __launch_bounds__(256) void scan1_kernel(const int* __restrict__ in,
                                                    int* __restrict__ out,
                                                    int* __restrict__ bsum, int M) {
  __shared__ int s[256];
  int t = threadIdx.x;
  int idx = blockIdx.x * 1024 + t * 4;
  int4 v = {0, 0, 0, 0};
  if (idx < M) v = *(const int4*)&in[idx];
  int tsum = v.x + v.y + v.z + v.w;
  s[t] = tsum;
  __syncthreads();
  for (int d = 1; d < 256; d <<= 1) {
    int tmp = (t >= d) ? s[t - d] : 0;
    __syncthreads();
    s[t] += tmp;
    __syncthreads();
  }
  int excl = s[t] - tsum;
  if (idx < M) {
    int4 o;
    o.x = excl; o.y = excl + v.x; o.z = o.y + v.y; o.w = o.z + v.z;
    *(int4*)&out[idx] = o;
  }
  if (t == 255) bsum[blockIdx.x] = s[255];
}

__global__ __launch_bounds__(256) void scan2_kernel(int* __restrict__ bsum, int nb,
                                                    int* __restrict__ ghist) {
  __shared__ int s[256];
  int t = threadIdx.x;
  if (t < 128) ghist[t] = 0;
  int v = (t < nb) ? bsum[t] : 0;
  s[t] = v;
  __syncthreads();
  for (int d = 1; d < 256; d <<= 1) {
    int tmp = (t >= d) ? s[t - d] : 0;
    __syncthreads();
    s[t] += tmp;
    __syncthreads();
  }
  if (t < nb) bsum[t] = s[t] - v;
}

__global__ __launch_bounds__(256) void scan3_kernel(int* __restrict__ out,
                                                    const int* __restrict__ bsum, int M,
                                                    int* __restrict__ bincur) {
  int idx = blockIdx.x * 1024 + threadIdx.x * 4;
  int add = bsum[blockIdx.x];
  if (idx < M) {
    int4 o = *(int4*)&out[idx];
    o.x += add; o.y += add; o.z += add; o.w += add;
    *(int4*)&out[idx] = o;
    int4 z = {0, 0, 0, 0};
    *(int4*)&bincur[idx] = z;
  }
}

// ---------------- two-level sort: scatter + dense fill ----------------

__global__ __launch_bounds__(256) void binscatter_kernel(const int* __restrict__ ei,
                                                         const int* __restrict__ ed,
                                                         const int* __restrict__ binoff,
                                                         int* __restrict__ bincur,
                                                         uint* __restrict__ binbuf,
                                                         float* __restrict__ comb_raw) {
  int gid = blockIdx.x * 256 + threadIdx.x;
  if (gid < kB * 256 / 4) {
    float4 z = {0.f, 0.f, 0.f, 0.f};
    *(float4*)&comb_raw[gid * 4] = z;
  }
  if (gid >= kE) return;
  int dst = ei[kE + gid];
  int ctr = ((ed[gid] * kBinsPerDir + (dst >> 8)) << 6) | ((gid >> 8) & 63);
  int pos = atomicAdd(&bincur[ctr], 1);
  binbuf[binoff[ctr] + pos] = (uint)ei[gid] | ((uint)(dst & 255) << 17);
}

__global__ __launch_bounds__(256) void binfill_kernel(const uint* __restrict__ binbuf,
                                                      const int* __restrict__ binoff,
                                                      int* __restrict__ csr,
                                                      int* __restrict__ cnt,
                                                      int* __restrict__ off,
                                                      int* __restrict__ ghist,
                                                      int* __restrict__ blockbase,
                                                      uint* __restrict__ perm) {
  __shared__ int lcnt[256];
  __shared__ int ls[256];
  __shared__ int lpos[256];
  int b = blockIdx.x;
  int t = threadIdx.x;
  perm[b * 256 + t] = (uint)kN;   // sentinel prefill (782*256 == 2*kNpad)
  int dir = (b >= kBinsPerDir) ? 1 : 0;
  int nodeBase = (b - dir * kBinsPerDir) << 8;
  int e0 = binoff[b * kRep];
  int e1 = (b == kNB - 1) ? kE : binoff[(b + 1) * kRep];
  lcnt[t] = 0;
  __syncthreads();
  for (int e = e0 + t; e < e1; e += 256) atomicAdd(&lcnt[binbuf[e] >> 17], 1);
  __syncthreads();
  int my = lcnt[t];
  ls[t] = my;
  __syncthreads();
  for (int d = 1; d < 256; d <<= 1) {
    int tmp = (t >= d) ? ls[t - d] : 0;
    __syncthreads();
    ls[t] += tmp;
    __syncthreads();
  }
  int excl = ls[t] - my;
  lpos[t] = e0 + excl;
  int node = nodeBase + t;
  if (node < kN) {
    int g = dir * kN + node;
    cnt[g] = my;
    off[g] = e0 + excl;
  }
  if (t < 64) lcnt[t] = 0;
  __syncthreads();
  if (node < kN) atomicAdd(&lcnt[min(my, 63)], 1);
  __syncthreads();
  if (t < 64) blockbase[b * 64 + t] = atomicAdd(&ghist[dir * 64 + t], lcnt[t]);
  __syncthreads();
  for (int e = e0 + t; e < e1; e += 256) {
    uint v = binbuf[e];
    int pos = atomicAdd(&lpos[v >> 17], 1);
    csr[pos] = (int)(v & 0x1FFFFu);
  }
}

// ---------------- degree-sort finish: scan + DESCENDING (LPT) scatter ----------------

__global__ __launch_bounds__(64) void dscan_kernel(int* __restrict__ ghist) {
  __shared__ int s[64];
  int t = threadIdx.x;
  for (int dir = 0; dir < 2; ++dir) {
    int v = ghist[dir * 64 + t];
    s[t] = v;
    __syncthreads();
    for (int d = 1; d < 64; d <<= 1) {
      int tmp = (t >= d) ? s[t - d] : 0;
      __syncthreads();
      s[t] += tmp;
      __syncthreads();
    }
    ghist[dir * 64 + t] = s[t] - v;
    __syncthreads();
  }
}

// descending-degree order: uniform-degree blocks, longest blocks scheduled first
// (LPT). Blocks drain as units -> LDS freed promptly -> high residency.
__global__ __launch_bounds__(256) void dscatter_kernel(const int* __restrict__ cnt,
                                                       const int* __restrict__ ghist,
                                                       const int* __restrict__ blockbase,
                                                       uint* __restrict__ perm) {
  __shared__ int h[64];
  int b = blockIdx.x;
  int t = threadIdx.x;
  int dir = (b >= kBinsPerDir) ? 1 : 0;
  int node = (b - dir * kBinsPerDir) * 256 + t;
  if (t < 64) h[t] = 0;
  __syncthreads();
  if (node < kN) {
    int bucket = min(cnt[dir * kN + node], 63);
    int r = atomicAdd(&h[bucket], 1);
    int pos = ghist[dir * 64 + bucket] + blockbase[b * 64 + bucket] + r;
    perm[dir * kNpad + (kN - 1 - pos)] = (uint)node;
  }
}

// ---------------- Fused SAGE layer (both directions in one dispatch) ----------------
// Barrier guards W stage only; two-wide gather; direct global stores.

__global__ __launch_bounds__(1024) void fused_layer_kernel(
    const ushort* __restrict__ hin0, const ushort* __restrict__ hin1,
    ushort* __restrict__ hout0, ushort* __restrict__ hout1,
    const ushort* __restrict__ Wb0, const ushort* __restrict__ Wb1,
    const float* __restrict__ bl0, const float* __restrict__ bl1,
    const int* __restrict__ off, const int* __restrict__ cnt,
    const int* __restrict__ csr, const uint* __restrict__ perm) {
  __shared__ ushort Wlds[128 * 256];   // 64 KB, 16B-block XOR swizzled

  const int dir = (blockIdx.x >= kTiles) ? 1 : 0;
  const int tile = blockIdx.x - dir * kTiles;
  const ushort* __restrict__ h = dir ? hin1 : hin0;
  ushort* __restrict__ outp = dir ? hout1 : hout0;
  const ushort* __restrict__ Wb = dir ? Wb1 : Wb0;
  const float* __restrict__ bl = dir ? bl1 : bl0;
  const uint* __restrict__ pp = perm + (size_t)dir * kNpad;
  const int dirbase = dir * kN;

  const int t = threadIdx.x;
  const int w = t >> 6;         // 0..15
  const int l = t & 63;
  const int lr = l & 15;
  const int lq = l >> 4;
  const int swz = lr & 7;

  // early per-lane loads (latency hides under W staging)
  const int node = (int)pp[tile * 256 + w * 16 + lr];  // pad -> kN
  int s = 0, c = 0;
  if (node < kN) {
    int bkt = dirbase + node;
    s = off[bkt];
    c = cnt[bkt];
  }
  s16x8 self[4];
#pragma unroll
  for (int q = 0; q < 4; ++q)
    self[q] = *(const s16x8*)(h + (size_t)node * 128 + q * 32 + lq * 8);

  // stage W, barrier right after
#pragma unroll
  for (int it = 0; it < 4; ++it) {
    int u = t + 1024 * it;  // u < 4096 16B-chunks
    int o = u >> 5, b = u & 31;
    uint4 v = *(const uint4*)(Wb + (size_t)u * 8);
    *(uint4*)((char*)Wlds + o * 512 + ((b ^ (o & 7)) << 4)) = v;
  }
  __syncthreads();

  // ---- gather + mean (registers only; no further barriers) ----
  float ga[32];
#pragma unroll
  for (int i = 0; i < 32; ++i) ga[i] = 0.f;
  {
    const ushort* hp = h + lq * 8;
    int e = 0;
    for (; e + 2 <= c; e += 2) {
      int s0 = csr[s + e];
      int s1 = csr[s + e + 1];
      const ushort* p0 = hp + (size_t)s0 * 128;
      const ushort* p1 = hp + (size_t)s1 * 128;
      uint4 va[4], vb[4];
#pragma unroll
      for (int q = 0; q < 4; ++q) va[q] = *(const uint4*)(p0 + q * 32);
#pragma unroll
      for (int q = 0; q < 4; ++q) vb[q] = *(const uint4*)(p1 + q * 32);
#pragma unroll
      for (int q = 0; q < 4; ++q) {
        ga[q * 8 + 0] += bflo(va[q].x) + bflo(vb[q].x);
        ga[q * 8 + 1] += bfhi(va[q].x) + bfhi(vb[q].x);
        ga[q * 8 + 2] += bflo(va[q].y) + bflo(vb[q].y);
        ga[q * 8 + 3] += bfhi(va[q].y) + bfhi(vb[q].y);
        ga[q * 8 + 4] += bflo(va[q].z) + bflo(vb[q].z);
        ga[q * 8 + 5] += bfhi(va[q].z) + bfhi(vb[q].z);
        ga[q * 8 + 6] += bflo(va[q].w) + bflo(vb[q].w);
        ga[q * 8 + 7] += bfhi(va[q].w) + bfhi(vb[q].w);
      }
    }
    if (e < c) {
      int s0 = csr[s + e];
      const ushort* p0 = hp + (size_t)s0 * 128;
      uint4 va[4];
#pragma unroll
      for (int q = 0; q < 4; ++q) va[q] = *(const uint4*)(p0 + q * 32);
#pragma unroll
      for (int q = 0; q < 4; ++q) {
        ga[q * 8 + 0] += bflo(va[q].x);
        ga[q * 8 + 1] += bfhi(va[q].x);
        ga[q * 8 + 2] += bflo(va[q].y);
        ga[q * 8 + 3] += bfhi(va[q].y);
        ga[q * 8 + 4] += bflo(va[q].z);
        ga[q * 8 + 5] += bfhi(va[q].z);
        ga[q * 8 + 6] += bflo(va[q].w);
        ga[q * 8 + 7] += bfhi(va[q].w);
      }
    }
  }
  float iv = 1.0f / fmaxf((float)c, 1.0f);
  s16x8 am[4];
#pragma unroll
  for (int q = 0; q < 4; ++q) {
    uint4 r;
    r.x = pack2(ga[q * 8 + 0] * iv, ga[q * 8 + 1] * iv);
    r.y = pack2(ga[q * 8 + 2] * iv, ga[q * 8 + 3] * iv);
    r.z = pack2(ga[q * 8 + 4] * iv, ga[q * 8 + 5] * iv);
    r.w = pack2(ga[q * 8 + 6] * iv, ga[q * 8 + 7] * iv);
    am[q] = __builtin_bit_cast(s16x8, r);
  }

  // ---- MFMA: 16 nodes x 128 outs, K=256 (mean regs | self regs) ----
  f32x4 acc[8];
#pragma unroll
  for (int j = 0; j < 8; ++j) acc[j] = {0.f, 0.f, 0.f, 0.f};

#pragma unroll
  for (int kk = 0; kk < 8; ++kk) {
    s16x8 a = (kk < 4) ? am[kk] : self[kk - 4];
    const int ks = (kk * 4 + lq) ^ swz;
#pragma unroll
    for (int j = 0; j < 8; ++j) {
      int o = j * 16 + lr;
      s16x8 wf = *(const s16x8*)((const char*)Wlds + o * 512 + (ks << 4));
      acc[j] = __builtin_amdgcn_mfma_f32_16x16x32_bf16(wf, a, acc[j], 0, 0, 0);
    }
  }

  if (node < kN) {
#pragma unroll
    for (int j = 0; j < 8; ++j) {
      int o = j * 16 + lq * 4;
      float4 bv = *(const float4*)(bl + o);
      ushort4 r;
      r.x = bf16rne(fmaxf(acc[j][0] + bv.x, 0.f));
      r.y = bf16rne(fmaxf(acc[j][1] + bv.y, 0.f));
      r.z = bf16rne(fmaxf(acc[j][2] + bv.z, 0.f));
      r.w = bf16rne(fmaxf(acc[j][3] + bv.w, 0.f));
      *(ushort4*)(outp + (size_t)node * 128 + o) = r;
    }
  }
}

// ---------------- Pooling: both directions, 16 chunks per graph ----------------

__global__ __launch_bounds__(256) void pool_kernel(const ushort* __restrict__ hp0,
                                                   const ushort* __restrict__ hp1,
                                                   const int* __restrict__ gstart,
                                                   float* __restrict__ comb_raw) {
  __shared__ float part[4 * 128];
  int gb = blockIdx.x;
  int dir = gb >> 11;            // kB*16 = 2048 blocks per dir
  int rem = gb & 2047;
  int graph = rem >> 4;
  int chunk = rem & 15;
  const ushort* __restrict__ h = dir ? hp1 : hp0;
  int base = dir << 7;
  int t = threadIdx.x;
  int slice = t >> 6;
  int col = t & 63;
  int s = gstart[graph];
  int e = gstart[graph + 1];
  int len = e - s;
  int c0 = s + (int)((long long)len * chunk / 16);
  int c1 = s + (int)((long long)len * (chunk + 1) / 16);
  float ax = 0.f, ay = 0.f;
  for (int n = c0 + slice; n < c1; n += 4) {
    uint v = *(const uint*)(h + (size_t)n * 128 + col * 2);
    ax += bflo(v);
    ay += bfhi(v);
  }
  part[slice * 128 + col * 2] = ax;
  part[slice * 128 + col * 2 + 1] = ay;
  __syncthreads();
  if (t < 128) {
    float v = part[t] + part[128 + t] + part[256 + t] + part[384 + t];
    atomicAdd(&comb_raw[graph * 256 + base + t], v);
  }
}

// ---------------- Heads ----------------

__global__ __launch_bounds__(256) void head_kernel(
    const float* __restrict__ comb_raw, const int* __restrict__ gstart,
    const float* __restrict__ gf,
    const float* __restrict__ neg, const float* __restrict__ neb,
    const float* __restrict__ fc1W, const float* __restrict__ fc1b,
    const float* __restrict__ bn1g, const float* __restrict__ bn1b,
    const float* __restrict__ fc2W, const float* __restrict__ fc2b,
    const float* __restrict__ fc3aW, const float* __restrict__ fc3ab,
    const float* __restrict__ fc3bW, const float* __restrict__ fc3bb,
    const float* __restrict__ ncg, const float* __restrict__ ncb,
    float* __restrict__ out) {
  __shared__ float wlds[6979];
  __shared__ float comb[256];
  __shared__ float x3[261];
  __shared__ float r2s[2];

  const int b = blockIdx.x;
  const int t = threadIdx.x;

  for (int i = t; i < 4112; i += 256) wlds[i] = fc1W[i];
  for (int i = t; i < 518; i += 256) wlds[4112 + i] = fc2W[i];
  for (int i = t; i < 1044; i += 256) wlds[4630 + i] = fc3aW[i];
  for (int i = t; i < 1305; i += 256) wlds[5674 + i] = fc3bW[i];

  float cntf = fmaxf((float)(gstart[b + 1] - gstart[b]), 1.0f);
  if (t < 256) comb[t] = neg[t] * ((comb_raw[b * 256 + t] / cntf) * kInvBN) + neb[t];
  __syncthreads();

  float g1 = gf[b * 5 + 1], g2 = gf[b * 5 + 2], g3 = gf[b * 5 + 3], g4 = gf[b * 5 + 4];
  const int g = t >> 3, l8 = t & 7;

  {
    float p = 0.f;
    if (g < 16) {
      const float* w = &wlds[g * 257];
      for (int j = l8; j < 256; j += 8) p += comb[j] * w[j];
    } else if (g < 18) {
      const float* w = &wlds[4112 + (g - 16) * 259];
      for (int j = l8; j < 256; j += 8) p += comb[j] * w[j];
    }
    p += __shfl_xor(p, 1);
    p += __shfl_xor(p, 2);
    p += __shfl_xor(p, 4);
    if (l8 == 0) {
      if (g < 16) {
        float z = fmaxf(p + wlds[g * 257 + 256] * g4 + fc1b[g], 0.f);
        out[b * 16 + g] = bn1g[g] * (z * kInvBN) + bn1b[g];
      } else if (g < 18) {
        int o = g - 16;
        const float* w = &wlds[4112 + o * 259];
        float z = fmaxf(p + w[256] * g2 + w[257] * g3 + w[258] * g4 + fc2b[o], 0.f);
        out[2048 + b * 2 + o] = z;
        r2s[o] = z;
      }
    }
  }
  for (int j = t; j < 261; j += 256) {
    float v;
    if (j < 256) v = comb[j];
    else if (j == 256) v = g2;
    else if (j == 257) v = g1;
    else if (j == 258) v = g2;
    else if (j == 259) v = g3;
    else v = g4;
    x3[j] = ncg[j] * (v * kInvBN) + ncb[j];
  }
  __syncthreads();
  int pred = (r2s[1] > r2s[0]) ? 1 : 0;

  {
    float p = 0.f;
    if (g < 4) {
      const float* w = &wlds[4630 + g * 261];
      for (int j = l8; j < 261; j += 8) p += x3[j] * w[j];
    } else if (g < 9) {
      const float* w = &wlds[5674 + (g - 4) * 261];
      for (int j = l8; j < 261; j += 8) p += x3[j] * w[j];
    }
    p += __shfl_xor(p, 1);
    p += __shfl_xor(p, 2);
    p += __shfl_xor(p, 4);
    if (l8 == 0) {
      if (g < 4) {
        float v = p + fc3ab[g];
        out[2304 + b * 9 + g] = (pred == 0) ? v : 0.f;
      } else if (g < 9) {
        int o = g - 4;
        float v = p + fc3bb[o];
        out[2304 + b * 9 + 4 + o] = (pred == 1) ? v : 0.f;
      }
    }
  }
}

// ---------------- Launch ----------------

extern "C" void kernel_launch(void* const* d_in, const int* in_sizes, int n_in,
                              void* d_out, int out_size, void* d_ws, size_t ws_size,
                              hipStream_t stream) {
  (void)in_sizes; (void)n_in; (void)out_size; (void)ws_size;
  const float* x   = (const float*)d_in[0];
  const int* ei    = (const int*)d_in[1];
  const int* ed    = (const int*)d_in[2];
  const int* batch = (const int*)d_in[3];
  const float* gf  = (const float*)d_in[4];

  char* ws = (char*)d_ws;
  auto carve = [&](size_t bytes) -> void* {
    void* p = ws;
    ws += (bytes + 255) & ~(size_t)255;
    return p;
  };
  int* cnt        = (int*)carve(2 * kN * sizeof(int));
  int* off        = (int*)carve(2 * kN * sizeof(int));
  int* bincnt     = (int*)carve(kCtrs * sizeof(int));
  int* bincur     = (int*)carve((kCtrs + 4) * sizeof(int));
  int* binoff     = (int*)carve((kCtrs + 4) * sizeof(int));
  int* bsum       = (int*)carve(1024);
  int* gstart     = (int*)carve((kB + 1) * sizeof(int));
  int* ghist      = (int*)carve(128 * sizeof(int));
  int* blockbase  = (int*)carve(kNB * 64 * sizeof(int));
  uint* perm      = (uint*)carve(2 * kNpad * sizeof(uint));
  int* csr        = (int*)carve(kE * sizeof(int));
  uint* binbuf    = (uint*)carve(kE * sizeof(uint));
  float* comb_raw = (float*)carve(kB * 256 * sizeof(float));
  ushort* xb      = (ushort*)carve((size_t)kNpad * 128 * 2);  // also reused as s1
  ushort* p0      = (ushort*)carve((size_t)kNpad * 128 * 2);
  ushort* p1      = (ushort*)carve((size_t)kNpad * 128 * 2);
  ushort* s0      = (ushort*)carve((size_t)kNpad * 128 * 2);
  ushort* Wb      = (ushort*)carve(6 * 128 * 256 * 2);

  hipMemsetAsync(bincnt, 0, kCtrs * sizeof(int), stream);

  WPtrs wp;
  for (int L = 0; L < 6; ++L) {
    wp.Wl[L] = (const float*)d_in[6 + 3 * L];
    wp.Wr[L] = (const float*)d_in[6 + 3 * L + 2];
  }

  prep_kernel<<<kPrepBlocks, 256, 0, stream>>>(x, xb, wp, Wb, ei, ed, bincnt, batch, gstart);

  constexpr int NBScan = (kCtrs + 1023) / 1024;  // 49
  scan1_kernel<<<NBScan, 256, 0, stream>>>(bincnt, binoff, bsum, kCtrs);
  scan2_kernel<<<1, 256, 0, stream>>>(bsum, NBScan, ghist);
  scan3_kernel<<<NBScan, 256, 0, stream>>>(binoff, bsum, kCtrs, bincur);
  binscatter_kernel<<<(kE + 255) / 256, 256, 0, stream>>>(ei, ed, binoff, bincur, binbuf, comb_raw);
  binfill_kernel<<<kNB, 256, 0, stream>>>(binbuf, binoff, csr, cnt, off, ghist, blockbase, perm);
  dscan_kernel<<<1, 64, 0, stream>>>(ghist);
  dscatter_kernel<<<kNB, 256, 0, stream>>>(cnt, ghist, blockbase, perm);

  auto W = [&](int L) { return Wb + (size_t)L * 32768; };
  auto B = [&](int L) { return (const float*)d_in[6 + 3 * L + 1]; };

  // L0: pre xb->p0, suc xb->s0
  fused_layer_kernel<<<2 * kTiles, 1024, 0, stream>>>(
      xb, xb, p0, s0, W(0), W(3), B(0), B(3), off, cnt, csr, perm);
  // L1: pre p0->p1, suc s0->xb (xb reused as s1)
  fused_layer_kernel<<<2 * kTiles, 1024, 0, stream>>>(
      p0, s0, p1, xb, W(1), W(4), B(1), B(4), off, cnt, csr, perm);
  // L2: pre p1->p0, suc xb->s0
  fused_layer_kernel<<<2 * kTiles, 1024, 0, stream>>>(
      p1, xb, p0, s0, W(2), W(5), B(2), B(5), off, cnt, csr, perm);

  pool_kernel<<<2 * kB * 16, 256, 0, stream>>>(p0, s0, gstart, comb_raw);

  head_kernel<<<kB, 256, 0, stream>>>(
      comb_raw, gstart, gf,
      (const float*)d_in[24], (const float*)d_in[25],
      (const float*)d_in[26], (const float*)d_in[27],
      (const float*)d_in[28], (const float*)d_in[29],
      (const float*)d_in[30], (const float*)d_in[31],
      (const float*)d_in[32], (const float*)d_in[33],
      (const float*)d_in[34], (const float*)d_in[35],
      (const float*)d_in[36], (const float*)d_in[37],
      (float*)d_out);
}